// Round 16
// baseline (171.007 us; speedup 1.0000x reference)
//
#include <hip/hip_runtime.h>
#include <hip/hip_bf16.h>

// B=8, C=256, H=W=32, N=HW=1024.
// Pipeline (all GEMMs C[M,N] = A[M,K] · Bt[N,K]^T, both K-contiguous):
//  prep   : weights fp32->bf16 (+bias concat) and x -> xT bf16 (one dispatch)
//  x1,x1T : merged 512-block dispatch (gemm_x1, runtime role per block)
//  gT|rT  = x1T·(wq||wv)^T + bias   gemm8p 256^2  stacked M=8192, N=2048, split
//  E      = bf16 exp(x1·gT^T)       gemm256+STATS (rsp/csp partials)
//  rs,cs  = stats_reduce (deterministic partial sums)
//  Et     = E^T                     et_trans (bf16 LDS transpose, coalesced)
//  PT     = gemm_dual2: (a/rs[col])*(rT·E^T) + (b/cs[row])*(Et·x1^T)
//  out    = w2·PT^T + b2(row)       gemm_pipe fp32
// R15 post-mortem: Et-fusion into the E-GEMM epilogue regressed (scattered
// 8B stores at 2KB stride inside the critical GEMM); reverted to et_trans.
// x1/x1T merge kept as the single surviving R15 change.

typedef __attribute__((ext_vector_type(4))) float f4;
typedef __attribute__((ext_vector_type(8))) short s8;
typedef __attribute__((ext_vector_type(4))) unsigned short us4;
typedef __attribute__((ext_vector_type(8))) unsigned short us8;

__device__ __forceinline__ unsigned short f2bf(float f) {
    __hip_bfloat16 h = __float2bfloat16(f);
    return __builtin_bit_cast(unsigned short, h);
}
__device__ __forceinline__ float bf2f(unsigned short u) {
    unsigned int x = ((unsigned int)u) << 16;
    return __builtin_bit_cast(float, x);
}

#define GAS(p) ((const __attribute__((address_space(1))) unsigned int*)(p))
#define LAS(p) ((__attribute__((address_space(3))) unsigned int*)(p))

// ---------------- prep: weight conversion + bias concat + x transpose ---------
__global__ __launch_bounds__(256) void prep(
    const float* __restrict__ w1, const float* __restrict__ wq,
    const float* __restrict__ wv, const float* __restrict__ w2,
    unsigned short* __restrict__ w1b, unsigned short* __restrict__ wqb,
    unsigned short* __restrict__ wvb, unsigned short* __restrict__ w2b,
    const float* __restrict__ bq, const float* __restrict__ bv,
    float* __restrict__ biasqv,
    const float* __restrict__ x, unsigned short* __restrict__ xT)
{
    __shared__ float tl[32][33];
    if (blockIdx.x < 2562) {
        long i = (long)blockIdx.x * 256 + threadIdx.x;  // float4 index
        if (i >= 655360) {                               // bias concat: 512 f4
            long j = i - 655360;
            if (j < 512) {
                f4 v = (j < 256) ? ((const f4*)bq)[j] : ((const f4*)bv)[j - 256];
                ((f4*)biasqv)[j] = v;
            }
            return;
        }
        const float* src; unsigned short* dst; long base;
        if (i < 65536)               { src = w1; dst = w1b; base = 0; }
        else if (i < 65536+262144)   { src = wq; dst = wqb; base = 65536; }
        else if (i < 65536+524288)   { src = wv; dst = wvb; base = 65536+262144; }
        else                         { src = w2; dst = w2b; base = 65536+524288; }
        long j = i - base;
        f4 v = ((const f4*)src)[j];
        us4 o;
        #pragma unroll
        for (int k = 0; k < 4; ++k) o[k] = f2bf(v[k]);
        ((us4*)dst)[j] = o;
    } else {
        const int idx = blockIdx.x - 2562;               // 2048 transpose blocks
        const int q0 = (idx & 31) * 32;
        const int c0 = ((idx >> 5) & 7) * 32;
        const int b  = idx >> 8;
        const int tx = threadIdx.x & 31, ty = threadIdx.x >> 5;  // ty 0..7
        #pragma unroll
        for (int j = 0; j < 4; ++j)
            tl[ty + j*8][tx] = x[((long)(b*256 + c0 + ty + j*8))*1024 + q0 + tx];
        __syncthreads();
        #pragma unroll
        for (int j = 0; j < 4; ++j)
            xT[((long)(b*1024 + q0 + ty + j*8))*256 + c0 + tx] = f2bf(tl[tx][ty + j*8]);
    }
}

// ============ 256x256 8-phase GEMM (m201-style), K=1024, stacked M ============
// BIAS: 0 none, 2 col. SPLIT: cols>=1024 -> Cv1. Output bf16.
template<int BIAS, int SPLIT>
__global__ __launch_bounds__(512, 2) void gemm8p(
    const unsigned short* __restrict__ A0, const unsigned short* __restrict__ Bt0,
    int lda, int ldb,
    void* __restrict__ Cv0, void* __restrict__ Cv1, int ldc,
    const float* __restrict__ bias)
{
    constexpr int NT = 16;                                   // K/64
    __shared__ __align__(16) unsigned short As[2][2][8192];  // [dbuf][kh][256*32] 64 KB
    __shared__ __align__(16) unsigned short Bs[2][2][8192];  // 64 KB

    const int gx = gridDim.x, gy = gridDim.y;
    const int nwg = gx * gy;
    int d = blockIdx.x + gx * blockIdx.y;
    int swz = (d & 7) * (nwg >> 3) + (d >> 3);
    const int bx = swz % gx;
    const int by = swz / gx;

    const int m0 = by * 256;
    const int n0 = bx * 256;
    const int t  = threadIdx.x;
    const int w  = t >> 6, l = t & 63;
    const int wr = w >> 2, wc = w & 3;          // 2 M-waves x 4 N-waves
    const int lr = l & 15, lg = l >> 4;

    const unsigned short* Asrc = A0  + (long)m0 * lda;
    const unsigned short* Bsrc = Bt0 + (long)n0 * ldb;

    const int rl4 = l >> 2;
    const int gsw = ((l & 3) ^ ((l >> 3) & 3)) * 8;  // element offset
    const int rsw = (lr >> 1) & 3;                    // read-side XOR

    auto stage = [&](const unsigned short* src, int ld_, unsigned short* slot,
                     int sp, int kh) {                // one half-slot: 2 gloads
        #pragma unroll
        for (int i = 0; i < 2; ++i) {
            const int rb = i*128 + w*16;
            __builtin_amdgcn_global_load_lds(
                GAS(src + (long)(rb + rl4)*ld_ + sp*64 + kh*32 + gsw),
                LAS(slot + rb*32), 16, 0, 0);
        }
    };

    f4 acc[8][4];
    #pragma unroll
    for (int i = 0; i < 8; ++i)
        #pragma unroll
        for (int j = 0; j < 4; ++j) acc[i][j] = (f4){0.f, 0.f, 0.f, 0.f};

    s8 aF[4], bF[4];
    auto rdA = [&](int db, int kh, int mh) {
        #pragma unroll
        for (int m = 0; m < 4; ++m) {
            const int R = wr*128 + mh*64 + m*16 + lr;
            aF[m] = *(const s8*)&As[db][kh][R*32 + ((lg ^ rsw) * 8)];
        }
    };
    auto rdB = [&](int db, int kh) {
        #pragma unroll
        for (int n = 0; n < 4; ++n) {
            const int R = wc*64 + n*16 + lr;
            bF[n] = *(const s8*)&Bs[db][kh][R*32 + ((lg ^ rsw) * 8)];
        }
    };

#define MM8(MH)                                                                  \
    __builtin_amdgcn_s_setprio(1);                                               \
    _Pragma("unroll")                                                            \
    for (int m_ = 0; m_ < 4; ++m_)                                               \
        _Pragma("unroll")                                                        \
        for (int n_ = 0; n_ < 4; ++n_)                                           \
            acc[(MH)*4 + m_][n_] = __builtin_amdgcn_mfma_f32_16x16x32_bf16(      \
                aF[m_], bF[n_], acc[(MH)*4 + m_][n_], 0, 0, 0);                  \
    __builtin_amdgcn_s_setprio(0);

#define PH8(DB, KH, MH, RB, STG, VM)                                             \
    rdA(DB, KH, MH);                                                             \
    if (RB) rdB(DB, KH);                                                         \
    STG;                                                                         \
    __builtin_amdgcn_sched_barrier(0);                                           \
    __builtin_amdgcn_s_barrier();                                                \
    asm volatile("s_waitcnt lgkmcnt(0)" ::: "memory");                           \
    __builtin_amdgcn_sched_barrier(0);                                           \
    MM8(MH);                                                                     \
    VM;                                                                          \
    __builtin_amdgcn_s_barrier();

    stage(Asrc, lda, &As[0][0][0], 0, 0);
    stage(Bsrc, ldb, &Bs[0][0][0], 0, 0);
    stage(Asrc, lda, &As[0][1][0], 0, 1);
    stage(Bsrc, ldb, &Bs[0][1][0], 0, 1);
    stage(Asrc, lda, &As[1][0][0], 1, 0);
    stage(Bsrc, ldb, &Bs[1][0][0], 1, 0);
    asm volatile("s_waitcnt vmcnt(4)" ::: "memory");
    __builtin_amdgcn_sched_barrier(0);
    __builtin_amdgcn_s_barrier();

    for (int j = 0; j < NT/2; ++j) {
        const int tb = 2*j + 1;
        const int t2 = (2*j + 2) & (NT - 1);
        const int t3 = (2*j + 3) & (NT - 1);
        PH8(0,0,0, 1, stage(Asrc, lda, &As[1][1][0], tb, 1), (void)0)
        PH8(0,0,1, 0, stage(Bsrc, ldb, &Bs[1][1][0], tb, 1), (void)0)
        PH8(0,1,0, 1, stage(Asrc, lda, &As[0][0][0], t2, 0), (void)0)
        PH8(0,1,1, 0, stage(Bsrc, ldb, &Bs[0][0][0], t2, 0),
            asm volatile("s_waitcnt vmcnt(4)" ::: "memory"))
        PH8(1,0,0, 1, stage(Asrc, lda, &As[0][1][0], t2, 1), (void)0)
        PH8(1,0,1, 0, stage(Bsrc, ldb, &Bs[0][1][0], t2, 1), (void)0)
        PH8(1,1,0, 1, stage(Asrc, lda, &As[1][0][0], t3, 0), (void)0)
        PH8(1,1,1, 0, stage(Bsrc, ldb, &Bs[1][0][0], t3, 0),
            asm volatile("s_waitcnt vmcnt(4)" ::: "memory"))
    }
#undef PH8
#undef MM8

    void* Cd = Cv0; int nbase = n0;
    if (SPLIT && n0 >= 1024) { Cd = Cv1; nbase = n0 - 1024; }

    const int rbase = lg * 4;
    #pragma unroll
    for (int mi = 0; mi < 8; ++mi) {
        #pragma unroll
        for (int n = 0; n < 4; ++n) {
            const int row  = m0 + wr*128 + mi*16 + rbase;
            const int col  = nbase + wc*64 + n*16 + lr;
            const int bcol = n0    + wc*64 + n*16 + lr;
            #pragma unroll
            for (int j = 0; j < 4; ++j) {
                float v = acc[mi][n][j];
                if (BIAS == 2) v += bias[bcol];
                ((unsigned short*)Cd)[(long)(row + j)*ldc + col] = f2bf(v);
            }
        }
    }
}

// ---------------- big-tile GEMM: 256x128, BK=64, 8 waves, piped reads ---------
// BIAS: 0 none, 1 row, 2 col. OUTF32: fp32 out. STATS: write bf16 exp(S) + row
// partials rsp[row][256] (p2=bx*32+wc*16+lr) + col partials csp[p][8192]
// (p=by*16+wr*4+lg); requires grid (8,4,8), bf16 out. Grid total % 8 == 0.
template<int BIAS, int OUTF32, int STATS>
__global__ __launch_bounds__(512, 2) void gemm256(
    const unsigned short* __restrict__ A0, const unsigned short* __restrict__ Bt0,
    long sA, long sB, int lda, int ldb,
    void* __restrict__ Cv0, long sC, int ldc,
    const float* __restrict__ bias, int nt1,
    float* __restrict__ csp, float* __restrict__ rsp)
{
    __shared__ __align__(16) unsigned short As[3][16384];   // 96 KB
    __shared__ __align__(16) unsigned short Bs[3][8192];    // 48 KB

    const int gx = gridDim.x, gy = gridDim.y;
    const int nwg = gx * gy * gridDim.z;
    int d = blockIdx.x + gx * (blockIdx.y + gy * blockIdx.z);
    int swz = (d & 7) * (nwg >> 3) + (d >> 3);
    const int bx = swz % gx; int tq = swz / gx;
    const int by = tq % gy;  const int bz = tq / gy;

    const int b  = bz;
    const int m0 = by * 256;
    const int n0 = bx * 128;
    const int t  = threadIdx.x;
    const int w  = t >> 6, l = t & 63;
    const int wr = w >> 1, wc = w & 1;          // 4 M-waves x 2 N-waves
    const int lr = l & 15, lg = l >> 4;

    const unsigned short* A0b = A0  + (long)b * sA;
    const unsigned short* B0b = Bt0 + (long)b * sB;

    const int rl  = l >> 3;
    const int gsw = ((l & 7) ^ (rl & 7)) * 8;

    const int NT = nt1;

    auto stageA = [&](int sp, int bf) {
        const int kt = sp * 64;
        #pragma unroll
        for (int i = 0; i < 4; ++i) {
            const int rb = w*32 + i*8;
            __builtin_amdgcn_global_load_lds(GAS(A0b + (long)(m0 + rb + rl)*lda + kt + gsw),
                                             LAS(&As[bf][rb*64]), 16, 0, 0);
        }
    };
    auto stageB = [&](int sp, int bf) {
        const int kt = sp * 64;
        #pragma unroll
        for (int i = 0; i < 2; ++i) {
            const int rb = w*16 + i*8;
            __builtin_amdgcn_global_load_lds(GAS(B0b + (long)(n0 + rb + rl)*ldb + kt + gsw),
                                             LAS(&Bs[bf][rb*64]), 16, 0, 0);
        }
    };

    f4 acc[4][4];
    #pragma unroll
    for (int i = 0; i < 4; ++i)
        #pragma unroll
        for (int j = 0; j < 4; ++j) acc[i][j] = (f4){0.f, 0.f, 0.f, 0.f};

    stageA(0, 0); stageB(0, 0);
    stageA(1, 1); stageB(1, 1);
    asm volatile("s_waitcnt vmcnt(6)" ::: "memory");
    __builtin_amdgcn_sched_barrier(0);
    __builtin_amdgcn_s_barrier();

    s8 a0[4], b0[4], a1f[4], b1f[4];

    #pragma unroll
    for (int m = 0; m < 4; ++m) {
        const int R = wr*64 + m*16 + lr;
        a0[m] = *(const s8*)&As[0][R*64 + ((lg ^ (R & 7)) * 8)];
    }
    #pragma unroll
    for (int n = 0; n < 4; ++n) {
        const int R = wc*64 + n*16 + lr;
        b0[n] = *(const s8*)&Bs[0][R*64 + ((lg ^ (R & 7)) * 8)];
    }
    asm volatile("s_waitcnt lgkmcnt(0)" ::: "memory");
    __builtin_amdgcn_sched_barrier(0);

    int buf = 0;
    for (int s = 0; s < NT; ++s) {
        int bn = buf + 2; if (bn >= 3) bn -= 3;
        int bx1 = buf + 1; if (bx1 >= 3) bx1 -= 3;

        #pragma unroll
        for (int m = 0; m < 4; ++m) {
            const int R = wr*64 + m*16 + lr;
            a1f[m] = *(const s8*)&As[buf][R*64 + (((4 + lg) ^ (R & 7)) * 8)];
        }
        #pragma unroll
        for (int n = 0; n < 4; ++n) {
            const int R = wc*64 + n*16 + lr;
            b1f[n] = *(const s8*)&Bs[buf][R*64 + (((4 + lg) ^ (R & 7)) * 8)];
        }
        if (s + 2 < NT) stageA(s + 2, bn);
        __builtin_amdgcn_s_setprio(1);
        #pragma unroll
        for (int m = 0; m < 4; ++m)
            #pragma unroll
            for (int n = 0; n < 4; ++n)
                acc[m][n] = __builtin_amdgcn_mfma_f32_16x16x32_bf16(a0[m], b0[n], acc[m][n], 0, 0, 0);
        __builtin_amdgcn_s_setprio(0);
        asm volatile("s_waitcnt lgkmcnt(0)" ::: "memory");
        __builtin_amdgcn_sched_barrier(0);

        if (s + 1 < NT) {
            if (s + 2 < NT) asm volatile("s_waitcnt vmcnt(4)" ::: "memory");
            else            asm volatile("s_waitcnt vmcnt(0)" ::: "memory");
            __builtin_amdgcn_sched_barrier(0);
            __builtin_amdgcn_s_barrier();
            #pragma unroll
            for (int m = 0; m < 4; ++m) {
                const int R = wr*64 + m*16 + lr;
                a0[m] = *(const s8*)&As[bx1][R*64 + ((lg ^ (R & 7)) * 8)];
            }
            #pragma unroll
            for (int n = 0; n < 4; ++n) {
                const int R = wc*64 + n*16 + lr;
                b0[n] = *(const s8*)&Bs[bx1][R*64 + ((lg ^ (R & 7)) * 8)];
            }
            if (s + 2 < NT) stageB(s + 2, bn);
            __builtin_amdgcn_s_setprio(1);
            #pragma unroll
            for (int m = 0; m < 4; ++m)
                #pragma unroll
                for (int n = 0; n < 4; ++n)
                    acc[m][n] = __builtin_amdgcn_mfma_f32_16x16x32_bf16(a1f[m], b1f[n], acc[m][n], 0, 0, 0);
            __builtin_amdgcn_s_setprio(0);
            asm volatile("s_waitcnt lgkmcnt(0)" ::: "memory");
            __builtin_amdgcn_sched_barrier(0);
        } else {
            __builtin_amdgcn_s_setprio(1);
            #pragma unroll
            for (int m = 0; m < 4; ++m)
                #pragma unroll
                for (int n = 0; n < 4; ++n)
                    acc[m][n] = __builtin_amdgcn_mfma_f32_16x16x32_bf16(a1f[m], b1f[n], acc[m][n], 0, 0, 0);
            __builtin_amdgcn_s_setprio(0);
        }

        buf = bx1;
    }

    const int rbase = lg * 4;
    float csum[4] = {0.f, 0.f, 0.f, 0.f};
    float rsum[16];
    #pragma unroll
    for (int i = 0; i < 16; ++i) rsum[i] = 0.f;

    #pragma unroll
    for (int m = 0; m < 4; ++m) {
        #pragma unroll
        for (int n = 0; n < 4; ++n) {
            const int row  = m0 + wr*64 + m*16 + rbase;
            const int col  = n0 + wc*64 + n*16 + lr;
            #pragma unroll
            for (int j = 0; j < 4; ++j) {
                float v = acc[m][n][j];
                if (BIAS == 1) v += bias[row + j];
                else if (BIAS == 2) v += bias[col];
                const long idx = (long)b*sC + (long)(row + j)*ldc + col;
                if (STATS) {
                    float ev = __expf(v);
                    unsigned short bv = f2bf(ev);
                    ((unsigned short*)Cv0)[idx] = bv;
                    float evr = bf2f(bv);
                    csum[n] += evr;
                    rsum[m*4 + j] += evr;
                } else if (OUTF32) {
                    ((float*)Cv0)[idx] = v;
                } else {
                    ((unsigned short*)Cv0)[idx] = f2bf(v);
                }
            }
        }
    }

    if (STATS) {
        const int p = by*16 + wr*4 + lg;          // 64 col-partials
        #pragma unroll
        for (int n = 0; n < 4; ++n) {
            const int col = n0 + wc*64 + n*16 + lr;
            csp[(long)p*8192 + b*1024 + col] = csum[n];
        }
        const int p2 = bx*32 + wc*16 + lr;        // 256 row-partials
        #pragma unroll
        for (int m = 0; m < 4; ++m)
            #pragma unroll
            for (int j = 0; j < 4; ++j) {
                const int row = m0 + wr*64 + m*16 + rbase + j;
                rsp[(long)(b*1024 + row)*256 + p2] = rsum[m*4 + j];
            }
    }
}

// ---------------- merged x1 / x1T kernel (512 blocks, runtime role) -----------
// by<4: x1 = w1·xT^T + b1(row), batch bz, m0=by*256.
// by>=4: x1T = xT·w1^T + b1(col), stacked tile bz*4+(by-4).
__global__ __launch_bounds__(512, 2) void gemm_x1(
    const unsigned short* __restrict__ w1b, const unsigned short* __restrict__ xTb,
    unsigned short* __restrict__ x1, unsigned short* __restrict__ x1T,
    const float* __restrict__ b1)
{
    constexpr int NT = 4;                                   // K=256
    __shared__ __align__(16) unsigned short As[3][16384];
    __shared__ __align__(16) unsigned short Bs[3][8192];

    const int gx = gridDim.x, gy = gridDim.y;
    const int nwg = gx * gy * gridDim.z;
    int d = blockIdx.x + gx * (blockIdx.y + gy * blockIdx.z);
    int swz = (d & 7) * (nwg >> 3) + (d >> 3);
    const int bx = swz % gx; int tq = swz / gx;
    const int by = tq % gy;  const int bz = tq / gy;

    const bool roleA = (by < 4);
    const unsigned short* Ap;
    const unsigned short* Bp;
    unsigned short* Cp;
    int m0;
    if (roleA) {
        Ap = w1b;
        Bp = xTb + (long)bz * 262144;
        Cp = x1  + (long)bz * 1048576;
        m0 = by * 256;
    } else {
        Ap = xTb;
        Bp = w1b;
        Cp = x1T;
        m0 = (bz * 4 + (by - 4)) * 256;
    }
    const int n0 = bx * 128;
    const int t  = threadIdx.x;
    const int w  = t >> 6, l = t & 63;
    const int wr = w >> 1, wc = w & 1;
    const int lr = l & 15, lg = l >> 4;

    const int rl  = l >> 3;
    const int gsw = ((l & 7) ^ (rl & 7)) * 8;

    auto stageA = [&](int sp, int bf) {
        const int kt = sp * 64;
        #pragma unroll
        for (int i = 0; i < 4; ++i) {
            const int rb = w*32 + i*8;
            __builtin_amdgcn_global_load_lds(GAS(Ap + (long)(m0 + rb + rl)*256 + kt + gsw),
                                             LAS(&As[bf][rb*64]), 16, 0, 0);
        }
    };
    auto stageB = [&](int sp, int bf) {
        const int kt = sp * 64;
        #pragma unroll
        for (int i = 0; i < 2; ++i) {
            const int rb = w*16 + i*8;
            __builtin_amdgcn_global_load_lds(GAS(Bp + (long)(n0 + rb + rl)*256 + kt + gsw),
                                             LAS(&Bs[bf][rb*64]), 16, 0, 0);
        }
    };

    f4 acc[4][4];
    #pragma unroll
    for (int i = 0; i < 4; ++i)
        #pragma unroll
        for (int j = 0; j < 4; ++j) acc[i][j] = (f4){0.f, 0.f, 0.f, 0.f};

    stageA(0, 0); stageB(0, 0);
    stageA(1, 1); stageB(1, 1);
    asm volatile("s_waitcnt vmcnt(6)" ::: "memory");
    __builtin_amdgcn_sched_barrier(0);
    __builtin_amdgcn_s_barrier();

    s8 a0[4], b0[4], a1f[4], b1f[4];

    #pragma unroll
    for (int m = 0; m < 4; ++m) {
        const int R = wr*64 + m*16 + lr;
        a0[m] = *(const s8*)&As[0][R*64 + ((lg ^ (R & 7)) * 8)];
    }
    #pragma unroll
    for (int n = 0; n < 4; ++n) {
        const int R = wc*64 + n*16 + lr;
        b0[n] = *(const s8*)&Bs[0][R*64 + ((lg ^ (R & 7)) * 8)];
    }
    asm volatile("s_waitcnt lgkmcnt(0)" ::: "memory");
    __builtin_amdgcn_sched_barrier(0);

    int buf = 0;
    for (int s = 0; s < NT; ++s) {
        int bn = buf + 2; if (bn >= 3) bn -= 3;
        int bx1 = buf + 1; if (bx1 >= 3) bx1 -= 3;

        #pragma unroll
        for (int m = 0; m < 4; ++m) {
            const int R = wr*64 + m*16 + lr;
            a1f[m] = *(const s8*)&As[buf][R*64 + (((4 + lg) ^ (R & 7)) * 8)];
        }
        #pragma unroll
        for (int n = 0; n < 4; ++n) {
            const int R = wc*64 + n*16 + lr;
            b1f[n] = *(const s8*)&Bs[buf][R*64 + (((4 + lg) ^ (R & 7)) * 8)];
        }
        if (s + 2 < NT) stageA(s + 2, bn);
        __builtin_amdgcn_s_setprio(1);
        #pragma unroll
        for (int m = 0; m < 4; ++m)
            #pragma unroll
            for (int n = 0; n < 4; ++n)
                acc[m][n] = __builtin_amdgcn_mfma_f32_16x16x32_bf16(a0[m], b0[n], acc[m][n], 0, 0, 0);
        __builtin_amdgcn_s_setprio(0);
        asm volatile("s_waitcnt lgkmcnt(0)" ::: "memory");
        __builtin_amdgcn_sched_barrier(0);

        if (s + 1 < NT) {
            if (s + 2 < NT) asm volatile("s_waitcnt vmcnt(4)" ::: "memory");
            else            asm volatile("s_waitcnt vmcnt(0)" ::: "memory");
            __builtin_amdgcn_sched_barrier(0);
            __builtin_amdgcn_s_barrier();
            #pragma unroll
            for (int m = 0; m < 4; ++m) {
                const int R = wr*64 + m*16 + lr;
                a0[m] = *(const s8*)&As[bx1][R*64 + ((lg ^ (R & 7)) * 8)];
            }
            #pragma unroll
            for (int n = 0; n < 4; ++n) {
                const int R = wc*64 + n*16 + lr;
                b0[n] = *(const s8*)&Bs[bx1][R*64 + ((lg ^ (R & 7)) * 8)];
            }
            if (s + 2 < NT) stageB(s + 2, bn);
            __builtin_amdgcn_s_setprio(1);
            #pragma unroll
            for (int m = 0; m < 4; ++m)
                #pragma unroll
                for (int n = 0; n < 4; ++n)
                    acc[m][n] = __builtin_amdgcn_mfma_f32_16x16x32_bf16(a1f[m], b1f[n], acc[m][n], 0, 0, 0);
            __builtin_amdgcn_s_setprio(0);
            asm volatile("s_waitcnt lgkmcnt(0)" ::: "memory");
            __builtin_amdgcn_sched_barrier(0);
        } else {
            __builtin_amdgcn_s_setprio(1);
            #pragma unroll
            for (int m = 0; m < 4; ++m)
                #pragma unroll
                for (int n = 0; n < 4; ++n)
                    acc[m][n] = __builtin_amdgcn_mfma_f32_16x16x32_bf16(a1f[m], b1f[n], acc[m][n], 0, 0, 0);
            __builtin_amdgcn_s_setprio(0);
        }

        buf = bx1;
    }

    const int rbase = lg * 4;
    #pragma unroll
    for (int m = 0; m < 4; ++m) {
        #pragma unroll
        for (int n = 0; n < 4; ++n) {
            const int row = m0 + wr*64 + m*16 + rbase;
            const int col = n0 + wc*64 + n*16 + lr;
            const float cb = roleA ? 0.f : b1[col];
            #pragma unroll
            for (int j = 0; j < 4; ++j) {
                float v = acc[m][n][j] + (roleA ? b1[(row + j) & 1023] : cb);
                Cp[(long)(row + j)*1024 + col] = f2bf(v);
            }
        }
    }
}

// ---------------- dual-accumulator GEMM: PT = s1(col)*A0B0 + s2(row)*A1B1 -----
__global__ __launch_bounds__(512, 2) void gemm_dual2(
    const unsigned short* __restrict__ A0, const unsigned short* __restrict__ Bt0,
    const unsigned short* __restrict__ A1, const unsigned short* __restrict__ Bt1,
    const float* __restrict__ rs, const float* __restrict__ cs,
    const float* __restrict__ alpha_p, const float* __restrict__ beta_p,
    unsigned short* __restrict__ C)
{
    constexpr int NT = 32;
    __shared__ __align__(16) unsigned short As[3][16384];
    __shared__ __align__(16) unsigned short Bs[3][8192];

    const int gx = gridDim.x, gy = gridDim.y;
    const int nwg = gx * gy * gridDim.z;
    int d = blockIdx.x + gx * (blockIdx.y + gy * blockIdx.z);
    int swz = (d & 7) * (nwg >> 3) + (d >> 3);
    const int bx = swz % gx; int tq = swz / gx;
    const int by = tq % gy;  const int bz = tq / gy;

    const int b  = bz;
    const int m0 = by * 256;
    const int n0 = bx * 128;
    const int t  = threadIdx.x;
    const int w  = t >> 6, l = t & 63;
    const int wr = w >> 1, wc = w & 1;
    const int lr = l & 15, lg = l >> 4;

    const unsigned short* A0b = A0  + (long)b * 1048576;
    const unsigned short* B0b = Bt0 + (long)b * 1048576;
    const unsigned short* A1b = A1  + (long)b * 1048576;
    const unsigned short* B1b = Bt1 + (long)b * 1048576;

    const int rl  = l >> 3;
    const int gsw = ((l & 7) ^ (rl & 7)) * 8;

    auto stageA = [&](int sp, int bf) {
        const unsigned short* Ap = (sp >= 16) ? A1b : A0b;
        const int kt = ((sp >= 16) ? sp - 16 : sp) * 64;
        #pragma unroll
        for (int i = 0; i < 4; ++i) {
            const int rb = w*32 + i*8;
            __builtin_amdgcn_global_load_lds(GAS(Ap + (long)(m0 + rb + rl)*1024 + kt + gsw),
                                             LAS(&As[bf][rb*64]), 16, 0, 0);
        }
    };
    auto stageB = [&](int sp, int bf) {
        const unsigned short* Bp = (sp >= 16) ? B1b : B0b;
        const int kt = ((sp >= 16) ? sp - 16 : sp) * 64;
        #pragma unroll
        for (int i = 0; i < 2; ++i) {
            const int rb = w*16 + i*8;
            __builtin_amdgcn_global_load_lds(GAS(Bp + (long)(n0 + rb + rl)*1024 + kt + gsw),
                                             LAS(&Bs[bf][rb*64]), 16, 0, 0);
        }
    };

    f4 acc1[4][4], acc2[4][4];
    #pragma unroll
    for (int i = 0; i < 4; ++i)
        #pragma unroll
        for (int j = 0; j < 4; ++j) {
            acc1[i][j] = (f4){0.f, 0.f, 0.f, 0.f};
            acc2[i][j] = (f4){0.f, 0.f, 0.f, 0.f};
        }

    stageA(0, 0); stageB(0, 0);
    stageA(1, 1); stageB(1, 1);
    asm volatile("s_waitcnt vmcnt(6)" ::: "memory");
    __builtin_amdgcn_sched_barrier(0);
    __builtin_amdgcn_s_barrier();

    s8 a0[4], b0[4], a1f[4], b1f[4];

    #pragma unroll
    for (int m = 0; m < 4; ++m) {
        const int R = wr*64 + m*16 + lr;
        a0[m] = *(const s8*)&As[0][R*64 + ((lg ^ (R & 7)) * 8)];
    }
    #pragma unroll
    for (int n = 0; n < 4; ++n) {
        const int R = wc*64 + n*16 + lr;
        b0[n] = *(const s8*)&Bs[0][R*64 + ((lg ^ (R & 7)) * 8)];
    }
    asm volatile("s_waitcnt lgkmcnt(0)" ::: "memory");
    __builtin_amdgcn_sched_barrier(0);

#define DUAL_BODY(ACC)                                                            \
    {                                                                             \
        int bn = buf + 2; if (bn >= 3) bn -= 3;                                   \
        int bx1 = buf + 1; if (bx1 >= 3) bx1 -= 3;                                \
        _Pragma("unroll")                                                         \
        for (int m = 0; m < 4; ++m) {                                             \
            const int R = wr*64 + m*16 + lr;                                      \
            a1f[m] = *(const s8*)&As[buf][R*64 + (((4 + lg) ^ (R & 7)) * 8)];     \
        }                                                                         \
        _Pragma("unroll")                                                         \
        for (int n = 0; n < 4; ++n) {                                             \
            const int R = wc*64 + n*16 + lr;                                      \
            b1f[n] = *(const s8*)&Bs[buf][R*64 + (((4 + lg) ^ (R & 7)) * 8)];     \
        }                                                                         \
        if (s + 2 < NT) stageA(s + 2, bn);                                        \
        __builtin_amdgcn_s_setprio(1);                                            \
        _Pragma("unroll")                                                         \
        for (int m = 0; m < 4; ++m)                                               \
            _Pragma("unroll")                                                     \
            for (int n = 0; n < 4; ++n)                                           \
                ACC[m][n] = __builtin_amdgcn_mfma_f32_16x16x32_bf16(a0[m], b0[n], ACC[m][n], 0, 0, 0); \
        __builtin_amdgcn_s_setprio(0);                                            \
        asm volatile("s_waitcnt lgkmcnt(0)" ::: "memory");                        \
        __builtin_amdgcn_sched_barrier(0);                                        \
        if (s + 1 < NT) {                                                         \
            if (s + 2 < NT) asm volatile("s_waitcnt vmcnt(4)" ::: "memory");      \
            else            asm volatile("s_waitcnt vmcnt(0)" ::: "memory");      \
            __builtin_amdgcn_sched_barrier(0);                                    \
            __builtin_amdgcn_s_barrier();                                         \
            _Pragma("unroll")                                                     \
            for (int m = 0; m < 4; ++m) {                                         \
                const int R = wr*64 + m*16 + lr;                                  \
                a0[m] = *(const s8*)&As[bx1][R*64 + ((lg ^ (R & 7)) * 8)];        \
            }                                                                     \
            _Pragma("unroll")                                                     \
            for (int n = 0; n < 4; ++n) {                                         \
                const int R = wc*64 + n*16 + lr;                                  \
                b0[n] = *(const s8*)&Bs[bx1][R*64 + ((lg ^ (R & 7)) * 8)];        \
            }                                                                     \
            if (s + 2 < NT) stageB(s + 2, bn);                                    \
            __builtin_amdgcn_s_setprio(1);                                        \
            _Pragma("unroll")                                                     \
            for (int m = 0; m < 4; ++m)                                           \
                _Pragma("unroll")                                                 \
                for (int n = 0; n < 4; ++n)                                       \
                    ACC[m][n] = __builtin_amdgcn_mfma_f32_16x16x32_bf16(a1f[m], b1f[n], ACC[m][n], 0, 0, 0); \
            __builtin_amdgcn_s_setprio(0);                                        \
            asm volatile("s_waitcnt lgkmcnt(0)" ::: "memory");                    \
            __builtin_amdgcn_sched_barrier(0);                                    \
        } else {                                                                  \
            __builtin_amdgcn_s_setprio(1);                                        \
            _Pragma("unroll")                                                     \
            for (int m = 0; m < 4; ++m)                                           \
                _Pragma("unroll")                                                 \
                for (int n = 0; n < 4; ++n)                                       \
                    ACC[m][n] = __builtin_amdgcn_mfma_f32_16x16x32_bf16(a1f[m], b1f[n], ACC[m][n], 0, 0, 0); \
            __builtin_amdgcn_s_setprio(0);                                        \
        }                                                                         \
        buf = bx1;                                                                \
    }

    int buf = 0;
    for (int s = 0; s < 16; ++s) DUAL_BODY(acc1)
    for (int s = 16; s < NT; ++s) DUAL_BODY(acc2)
#undef DUAL_BODY

    const float al = alpha_p[0], be = beta_p[0];
    const int rbase = lg * 4;
    float rscv[4];
    #pragma unroll
    for (int n = 0; n < 4; ++n)
        rscv[n] = al / rs[b*1024 + n0 + wc*64 + n*16 + lr];

    #pragma unroll
    for (int m = 0; m < 4; ++m) {
        #pragma unroll
        for (int j = 0; j < 4; ++j) {
            const int row = m0 + wr*64 + m*16 + rbase + j;
            const float csc = be / cs[b*1024 + row];
            #pragma unroll
            for (int n = 0; n < 4; ++n) {
                const int col = n0 + wc*64 + n*16 + lr;
                float v = acc1[m][n][j]*rscv[n] + acc2[m][n][j]*csc;
                C[(long)b*1048576 + (long)row*1024 + col] = f2bf(v);
            }
        }
    }
}

// ---------------- 128x128 pipelined GEMM (out projection) ---------------------
template<int BIAS, int OUTF32, int NT1, int NBUF>
__global__ __launch_bounds__(256) void gemm_pipe(
    const unsigned short* __restrict__ A0, const unsigned short* __restrict__ Bt0,
    long sA, long sB, int lda, int ldb,
    void* __restrict__ Cv0, long sC, int ldc,
    const float* __restrict__ bias)
{
    constexpr int NT = NT1;
    __shared__ __align__(16) unsigned short As[NBUF][4096];
    __shared__ __align__(16) unsigned short Bs[NBUF][4096];

    const int gx = gridDim.x, gy = gridDim.y;
    const int nwg = gx * gy * gridDim.z;
    int d = blockIdx.x + gx * (blockIdx.y + gy * blockIdx.z);
    int swz = (d & 7) * (nwg >> 3) + (d >> 3);
    const int bx = swz % gx; int tq = swz / gx;
    const int by = tq % gy;  const int bz = tq / gy;

    const int b  = bz;
    const int m0 = by * 128;
    const int n0 = bx * 128;
    const int t  = threadIdx.x;
    const int w  = t >> 6, l = t & 63;
    const int wr = w >> 1, wc = w & 1;
    const int lr = l & 15;

    const unsigned short* A0b = A0  + (long)b * sA;
    const unsigned short* B0b = Bt0 + (long)b * sB;

    const int rA   = w*32 + (l >> 2);
    const int cswz = ((l & 3) ^ ((l >> 3) & 3)) * 8;
    const int swzr = (((l >> 4) ^ ((lr >> 1) & 3)) * 8);

    f4 acc[4][4];
    #pragma unroll
    for (int i = 0; i < 4; ++i)
        #pragma unroll
        for (int j = 0; j < 4; ++j) acc[i][j] = (f4){0.f, 0.f, 0.f, 0.f};

    auto stage = [&](int sp, int bf) {
        const int kt = sp * 32;
        __builtin_amdgcn_global_load_lds(GAS(A0b + (long)(m0 + rA     )*lda + kt + cswz), LAS(&As[bf][w*1024      ]), 16, 0, 0);
        __builtin_amdgcn_global_load_lds(GAS(A0b + (long)(m0 + rA + 16)*lda + kt + cswz), LAS(&As[bf][w*1024 + 512]), 16, 0, 0);
        __builtin_amdgcn_global_load_lds(GAS(B0b + (long)(n0 + rA     )*ldb + kt + cswz), LAS(&Bs[bf][w*1024      ]), 16, 0, 0);
        __builtin_amdgcn_global_load_lds(GAS(B0b + (long)(n0 + rA + 16)*ldb + kt + cswz), LAS(&Bs[bf][w*1024 + 512]), 16, 0, 0);
    };

    #pragma unroll
    for (int dpl = 0; dpl < NBUF - 1; ++dpl) stage(dpl, dpl);

    int buf = 0;
    for (int s = 0; s < NT; ++s) {
        if (NBUF >= 4 && s + 2 < NT) asm volatile("s_waitcnt vmcnt(8)" ::: "memory");
        else if (s + 1 < NT)         asm volatile("s_waitcnt vmcnt(4)" ::: "memory");
        else                         asm volatile("s_waitcnt vmcnt(0)" ::: "memory");
        __builtin_amdgcn_s_barrier();
        __builtin_amdgcn_sched_barrier(0);

        s8 aF[4], bF[4];
        #pragma unroll
        for (int m = 0; m < 4; ++m) aF[m] = *(const s8*)&As[buf][(wr*64 + m*16 + lr)*32 + swzr];
        #pragma unroll
        for (int n = 0; n < 4; ++n) bF[n] = *(const s8*)&Bs[buf][(wc*64 + n*16 + lr)*32 + swzr];

        if (s + NBUF - 1 < NT) {
            int bn = buf + NBUF - 1; if (bn >= NBUF) bn -= NBUF;
            stage(s + NBUF - 1, bn);
        }

        __builtin_amdgcn_s_setprio(1);
        #pragma unroll
        for (int m = 0; m < 4; ++m)
            #pragma unroll
            for (int n = 0; n < 4; ++n)
                acc[m][n] = __builtin_amdgcn_mfma_f32_16x16x32_bf16(aF[m], bF[n], acc[m][n], 0, 0, 0);
        __builtin_amdgcn_s_setprio(0);

        if (++buf == NBUF) buf = 0;
    }

    const int rbase = (l >> 4) * 4;
    #pragma unroll
    for (int m = 0; m < 4; ++m) {
        #pragma unroll
        for (int n = 0; n < 4; ++n) {
            const int row = m0 + wr*64 + m*16 + rbase;
            const int col = n0 + wc*64 + n*16 + lr;
            #pragma unroll
            for (int j = 0; j < 4; ++j) {
                float v = acc[m][n][j];
                if (BIAS == 1) v += bias[row + j];
                else if (BIAS == 2) v += bias[col];
                const long idx = (long)b*sC + (long)(row + j)*ldc + col;
                if (OUTF32) ((float*)Cv0)[idx] = v;
                else ((unsigned short*)Cv0)[idx] = f2bf(v);
            }
        }
    }
}

// ---------------- stats reduce: cs[q] = sum csp; rs[row] = sum rsp ------------
__global__ __launch_bounds__(256) void stats_reduce(
    const float* __restrict__ csp, const float* __restrict__ rsp,
    float* __restrict__ cs, float* __restrict__ rs)
{
    if (blockIdx.x < 32) {
        const int q = blockIdx.x * 256 + threadIdx.x;   // 8192
        float s = 0.f;
        #pragma unroll
        for (int p = 0; p < 64; ++p) s += csp[(long)p*8192 + q];
        cs[q] = s;
    } else {
        const int blk = blockIdx.x - 32;                // 0..511, 16 rows each
        const int w = threadIdx.x >> 6, l = threadIdx.x & 63;
        #pragma unroll
        for (int i = 0; i < 4; ++i) {
            const int row = blk*16 + w*4 + i;
            f4 v = *(const f4*)&rsp[(long)row*256 + l*4];
            float s = v[0] + v[1] + v[2] + v[3];
            #pragma unroll
            for (int off = 32; off; off >>= 1) s += __shfl_xor(s, off);
            if (l == 0) rs[row] = s;
        }
    }
}

// ---------------- Et = E^T per batch (bf16 LDS transpose) ---------------------
__global__ __launch_bounds__(256) void et_trans(
    const unsigned short* __restrict__ E, unsigned short* __restrict__ Et)
{
    __shared__ unsigned short tile[64][65];
    const int b  = blockIdx.z;
    const int i0 = blockIdx.x * 64;
    const int q0 = blockIdx.y * 64;
    const int t  = threadIdx.x;
    const int ch = t & 7, r = t >> 3;    // r 0..31
    const unsigned short* Eb = E + (long)b * 1048576;
    #pragma unroll
    for (int pp = 0; pp < 2; ++pp) {
        const int rr = r + pp*32;
        us8 v = *(const us8*)&Eb[(long)(i0 + rr)*1024 + q0 + ch*8];
        #pragma unroll
        for (int e = 0; e < 8; ++e) tile[rr][ch*8 + e] = v[e];
    }
    __syncthreads();
    unsigned short* Etb = Et + (long)b * 1048576;
    #pragma unroll
    for (int pp = 0; pp < 2; ++pp) {
        const int qr = r + pp*32;
        us8 o;
        #pragma unroll
        for (int e = 0; e < 8; ++e) o[e] = tile[ch*8 + e][qr];
        *(us8*)&Etb[(long)(q0 + qr)*1024 + i0 + ch*8] = o;
    }
}

// -----------------------------------------------------------------------------
extern "C" void kernel_launch(void* const* d_in, const int* in_sizes, int n_in,
                              void* d_out, int out_size, void* d_ws, size_t ws_size,
                              hipStream_t stream)
{
    const float* x     = (const float*)d_in[0];
    const float* w1    = (const float*)d_in[1];
    const float* b1    = (const float*)d_in[2];
    const float* wq    = (const float*)d_in[3];
    const float* bq    = (const float*)d_in[4];
    const float* wv    = (const float*)d_in[5];
    const float* bv    = (const float*)d_in[6];
    const float* w2    = (const float*)d_in[7];
    const float* b2    = (const float*)d_in[8];
    const float* alpha = (const float*)d_in[9];
    const float* beta  = (const float*)d_in[10];
    float* out = (float*)d_out;

    char* ws = (char*)d_ws;
    size_t off = 0;
    auto alloc = [&](size_t bytes) -> void* {
        void* p = ws + off; off += (bytes + 255) & ~(size_t)255; return p;
    };
    unsigned short* w1b   = (unsigned short*)alloc(1024L*256*2);      // .5 MB
    unsigned short* wqvb  = (unsigned short*)alloc(2048L*1024*2);     //  4 MB (wq||wv)
    unsigned short* w2b   = (unsigned short*)alloc(256L*1024*2);      // .5 MB
    float*          biasqv= (float*)alloc(2048L*4);                   //  8 KB
    float*          cspv  = (float*)alloc(64L*8192*4);                //  2 MB
    float*          rspv  = (float*)alloc(8192L*256*4);               //  8 MB
    float*          csv   = (float*)alloc(8L*1024*4);                 // 32 KB
    float*          rsv   = (float*)alloc(8L*1024*4);                 // 32 KB
    unsigned short* xTb   = (unsigned short*)alloc(8L*1024*256*2);    //  4 MB
    unsigned short* x1b   = (unsigned short*)alloc(8L*1024*1024*2);   // 16 MB
    unsigned short* x1tb  = (unsigned short*)alloc(8L*1024*1024*2);   // 16 MB
    unsigned short* gtb   = (unsigned short*)alloc(8L*1024*1024*2);   // 16 MB
    unsigned short* rtb   = (unsigned short*)alloc(8L*1024*1024*2);   // 16 MB
    unsigned short* Ptb   = (unsigned short*)alloc(8L*1024*1024*2);   // 16 MB
    // lifetime aliases:
    unsigned short* Eb  = x1tb;   // x1tb (x1T) dead after gT|rT GEMM -> E
    unsigned short* Etb = gtb;    // gtb (gT) dead after E GEMM -> Et

    const long S1M = 1048576;

    // prep: weights + bias concat + x transpose (one dispatch)
    prep<<<4610, 256, 0, stream>>>(w1, wq, wv, w2, w1b, wqvb, wqvb + S1M, w2b,
                                   bq, bv, biasqv, x, xTb);

    // x1 and x1T merged (512 blocks)
    gemm_x1<<<dim3(8, 8, 8), 512, 0, stream>>>(w1b, xTb, x1b, x1tb, b1);
    // gT|rT = x1T·(wq||wv)^T + bias(col)   stacked M=8192, N=2048, split
    gemm8p<2,1><<<dim3(8, 32), 512, 0, stream>>>(
        x1tb, wqvb, 1024, 1024, gtb, rtb, 1024, biasqv);
    // E = bf16 exp(x1·gT^T) + row/col partials   z-batched (256 blocks)
    gemm256<0,0,1><<<dim3(8, 4, 8), 512, 0, stream>>>(
        x1b, gtb, S1M, S1M, 1024, 1024, Eb, S1M, 1024, nullptr, 16, cspv, rspv);
    // rs, cs
    stats_reduce<<<544, 256, 0, stream>>>(cspv, rspv, csv, rsv);
    // Et = E^T
    et_trans<<<dim3(16, 16, 8), 256, 0, stream>>>(Eb, Etb);
    // PT = (a/rs[col])·(rT·E^T) + (b/cs[row])·(Et·x1^T)   (256 blocks)
    gemm_dual2<<<dim3(8, 4, 8), 512, 0, stream>>>(
        rtb, Eb, Etb, x1b, rsv, csv, alpha, beta, Ptb);
    // out = w2·PT^T + b2(row), fp32        (128 blocks, depth-3)
    gemm_pipe<1,1,32,4><<<dim3(8, 2, 8), 256, 0, stream>>>(
        w2b, Ptb, 0, S1M, 1024, 1024, out, 262144, 1024, b2);
}

// Round 17
// 160.460 us; speedup vs baseline: 1.0657x; 1.0657x over previous
//
#include <hip/hip_runtime.h>
#include <hip/hip_bf16.h>

// B=8, C=256, H=W=32, N=HW=1024.
// Pipeline (all GEMMs C[M,N] = A[M,K] · Bt[N,K]^T, both K-contiguous):
//  prep   : weights fp32->bf16 (+bias concat) and x -> xT bf16 (one dispatch)
//  x1     = w1·xT^T + b1(row)       gemm256        [8][chan,hw]
//  x1T    = xT·w1^T + b1(col)       gemm256        stacked M=8192
//  gT|rT  = x1T·(wq||wv)^T + bias   gemm8p 256^2   stacked M=8192, N=2048, split
//  E      = bf16 exp(x1·gT^T)       gemm256+STATS  (rsp/csp partials)
//  rs,cs  = stats_reduce (deterministic partial sums)
//  Et     = E^T                     et_trans (bf16 LDS transpose, coalesced)
//  PT     = gemm_dual2: (a/rs[col])*(rT·E^T) + (b/cs[row])*(Et·x1^T)
//  out    = w2·PT^T + b2(row)       gemm_pipe fp32
// This is the R14 configuration (best measured: 160.7 us). R15's Et-fusion
// (scattered 8B stores in the GEMM epilogue) and R16's x1/x1T merge (breaks
// XCD-swizzle L2 locality; the two dispatches already overlap) both regressed
// and are reverted.

typedef __attribute__((ext_vector_type(4))) float f4;
typedef __attribute__((ext_vector_type(8))) short s8;
typedef __attribute__((ext_vector_type(4))) unsigned short us4;
typedef __attribute__((ext_vector_type(8))) unsigned short us8;

__device__ __forceinline__ unsigned short f2bf(float f) {
    __hip_bfloat16 h = __float2bfloat16(f);
    return __builtin_bit_cast(unsigned short, h);
}
__device__ __forceinline__ float bf2f(unsigned short u) {
    unsigned int x = ((unsigned int)u) << 16;
    return __builtin_bit_cast(float, x);
}

#define GAS(p) ((const __attribute__((address_space(1))) unsigned int*)(p))
#define LAS(p) ((__attribute__((address_space(3))) unsigned int*)(p))

// ---------------- prep: weight conversion + bias concat + x transpose ---------
__global__ __launch_bounds__(256) void prep(
    const float* __restrict__ w1, const float* __restrict__ wq,
    const float* __restrict__ wv, const float* __restrict__ w2,
    unsigned short* __restrict__ w1b, unsigned short* __restrict__ wqb,
    unsigned short* __restrict__ wvb, unsigned short* __restrict__ w2b,
    const float* __restrict__ bq, const float* __restrict__ bv,
    float* __restrict__ biasqv,
    const float* __restrict__ x, unsigned short* __restrict__ xT)
{
    __shared__ float tl[32][33];
    if (blockIdx.x < 2562) {
        long i = (long)blockIdx.x * 256 + threadIdx.x;  // float4 index
        if (i >= 655360) {                               // bias concat: 512 f4
            long j = i - 655360;
            if (j < 512) {
                f4 v = (j < 256) ? ((const f4*)bq)[j] : ((const f4*)bv)[j - 256];
                ((f4*)biasqv)[j] = v;
            }
            return;
        }
        const float* src; unsigned short* dst; long base;
        if (i < 65536)               { src = w1; dst = w1b; base = 0; }
        else if (i < 65536+262144)   { src = wq; dst = wqb; base = 65536; }
        else if (i < 65536+524288)   { src = wv; dst = wvb; base = 65536+262144; }
        else                         { src = w2; dst = w2b; base = 65536+524288; }
        long j = i - base;
        f4 v = ((const f4*)src)[j];
        us4 o;
        #pragma unroll
        for (int k = 0; k < 4; ++k) o[k] = f2bf(v[k]);
        ((us4*)dst)[j] = o;
    } else {
        const int idx = blockIdx.x - 2562;               // 2048 transpose blocks
        const int q0 = (idx & 31) * 32;
        const int c0 = ((idx >> 5) & 7) * 32;
        const int b  = idx >> 8;
        const int tx = threadIdx.x & 31, ty = threadIdx.x >> 5;  // ty 0..7
        #pragma unroll
        for (int j = 0; j < 4; ++j)
            tl[ty + j*8][tx] = x[((long)(b*256 + c0 + ty + j*8))*1024 + q0 + tx];
        __syncthreads();
        #pragma unroll
        for (int j = 0; j < 4; ++j)
            xT[((long)(b*1024 + q0 + ty + j*8))*256 + c0 + tx] = f2bf(tl[tx][ty + j*8]);
    }
}

// ============ 256x256 8-phase GEMM (m201-style), K=1024, stacked M ============
// BIAS: 0 none, 2 col. SPLIT: cols>=1024 -> Cv1. Output bf16.
template<int BIAS, int SPLIT>
__global__ __launch_bounds__(512, 2) void gemm8p(
    const unsigned short* __restrict__ A0, const unsigned short* __restrict__ Bt0,
    int lda, int ldb,
    void* __restrict__ Cv0, void* __restrict__ Cv1, int ldc,
    const float* __restrict__ bias)
{
    constexpr int NT = 16;                                   // K/64
    __shared__ __align__(16) unsigned short As[2][2][8192];  // [dbuf][kh][256*32] 64 KB
    __shared__ __align__(16) unsigned short Bs[2][2][8192];  // 64 KB

    const int gx = gridDim.x, gy = gridDim.y;
    const int nwg = gx * gy;
    int d = blockIdx.x + gx * blockIdx.y;
    int swz = (d & 7) * (nwg >> 3) + (d >> 3);
    const int bx = swz % gx;
    const int by = swz / gx;

    const int m0 = by * 256;
    const int n0 = bx * 256;
    const int t  = threadIdx.x;
    const int w  = t >> 6, l = t & 63;
    const int wr = w >> 2, wc = w & 3;          // 2 M-waves x 4 N-waves
    const int lr = l & 15, lg = l >> 4;

    const unsigned short* Asrc = A0  + (long)m0 * lda;
    const unsigned short* Bsrc = Bt0 + (long)n0 * ldb;

    const int rl4 = l >> 2;
    const int gsw = ((l & 3) ^ ((l >> 3) & 3)) * 8;  // element offset
    const int rsw = (lr >> 1) & 3;                    // read-side XOR

    auto stage = [&](const unsigned short* src, int ld_, unsigned short* slot,
                     int sp, int kh) {                // one half-slot: 2 gloads
        #pragma unroll
        for (int i = 0; i < 2; ++i) {
            const int rb = i*128 + w*16;
            __builtin_amdgcn_global_load_lds(
                GAS(src + (long)(rb + rl4)*ld_ + sp*64 + kh*32 + gsw),
                LAS(slot + rb*32), 16, 0, 0);
        }
    };

    f4 acc[8][4];
    #pragma unroll
    for (int i = 0; i < 8; ++i)
        #pragma unroll
        for (int j = 0; j < 4; ++j) acc[i][j] = (f4){0.f, 0.f, 0.f, 0.f};

    s8 aF[4], bF[4];
    auto rdA = [&](int db, int kh, int mh) {
        #pragma unroll
        for (int m = 0; m < 4; ++m) {
            const int R = wr*128 + mh*64 + m*16 + lr;
            aF[m] = *(const s8*)&As[db][kh][R*32 + ((lg ^ rsw) * 8)];
        }
    };
    auto rdB = [&](int db, int kh) {
        #pragma unroll
        for (int n = 0; n < 4; ++n) {
            const int R = wc*64 + n*16 + lr;
            bF[n] = *(const s8*)&Bs[db][kh][R*32 + ((lg ^ rsw) * 8)];
        }
    };

#define MM8(MH)                                                                  \
    __builtin_amdgcn_s_setprio(1);                                               \
    _Pragma("unroll")                                                            \
    for (int m_ = 0; m_ < 4; ++m_)                                               \
        _Pragma("unroll")                                                        \
        for (int n_ = 0; n_ < 4; ++n_)                                           \
            acc[(MH)*4 + m_][n_] = __builtin_amdgcn_mfma_f32_16x16x32_bf16(      \
                aF[m_], bF[n_], acc[(MH)*4 + m_][n_], 0, 0, 0);                  \
    __builtin_amdgcn_s_setprio(0);

#define PH8(DB, KH, MH, RB, STG, VM)                                             \
    rdA(DB, KH, MH);                                                             \
    if (RB) rdB(DB, KH);                                                         \
    STG;                                                                         \
    __builtin_amdgcn_sched_barrier(0);                                           \
    __builtin_amdgcn_s_barrier();                                                \
    asm volatile("s_waitcnt lgkmcnt(0)" ::: "memory");                           \
    __builtin_amdgcn_sched_barrier(0);                                           \
    MM8(MH);                                                                     \
    VM;                                                                          \
    __builtin_amdgcn_s_barrier();

    stage(Asrc, lda, &As[0][0][0], 0, 0);
    stage(Bsrc, ldb, &Bs[0][0][0], 0, 0);
    stage(Asrc, lda, &As[0][1][0], 0, 1);
    stage(Bsrc, ldb, &Bs[0][1][0], 0, 1);
    stage(Asrc, lda, &As[1][0][0], 1, 0);
    stage(Bsrc, ldb, &Bs[1][0][0], 1, 0);
    asm volatile("s_waitcnt vmcnt(4)" ::: "memory");
    __builtin_amdgcn_sched_barrier(0);
    __builtin_amdgcn_s_barrier();

    for (int j = 0; j < NT/2; ++j) {
        const int tb = 2*j + 1;
        const int t2 = (2*j + 2) & (NT - 1);
        const int t3 = (2*j + 3) & (NT - 1);
        PH8(0,0,0, 1, stage(Asrc, lda, &As[1][1][0], tb, 1), (void)0)
        PH8(0,0,1, 0, stage(Bsrc, ldb, &Bs[1][1][0], tb, 1), (void)0)
        PH8(0,1,0, 1, stage(Asrc, lda, &As[0][0][0], t2, 0), (void)0)
        PH8(0,1,1, 0, stage(Bsrc, ldb, &Bs[0][0][0], t2, 0),
            asm volatile("s_waitcnt vmcnt(4)" ::: "memory"))
        PH8(1,0,0, 1, stage(Asrc, lda, &As[0][1][0], t2, 1), (void)0)
        PH8(1,0,1, 0, stage(Bsrc, ldb, &Bs[0][1][0], t2, 1), (void)0)
        PH8(1,1,0, 1, stage(Asrc, lda, &As[1][0][0], t3, 0), (void)0)
        PH8(1,1,1, 0, stage(Bsrc, ldb, &Bs[1][0][0], t3, 0),
            asm volatile("s_waitcnt vmcnt(4)" ::: "memory"))
    }
#undef PH8
#undef MM8

    void* Cd = Cv0; int nbase = n0;
    if (SPLIT && n0 >= 1024) { Cd = Cv1; nbase = n0 - 1024; }

    const int rbase = lg * 4;
    #pragma unroll
    for (int mi = 0; mi < 8; ++mi) {
        #pragma unroll
        for (int n = 0; n < 4; ++n) {
            const int row  = m0 + wr*128 + mi*16 + rbase;
            const int col  = nbase + wc*64 + n*16 + lr;
            const int bcol = n0    + wc*64 + n*16 + lr;
            #pragma unroll
            for (int j = 0; j < 4; ++j) {
                float v = acc[mi][n][j];
                if (BIAS == 2) v += bias[bcol];
                ((unsigned short*)Cd)[(long)(row + j)*ldc + col] = f2bf(v);
            }
        }
    }
}

// ---------------- big-tile GEMM: 256x128, BK=64, 8 waves, piped reads ---------
// BIAS: 0 none, 1 row, 2 col. OUTF32: fp32 out. STATS: write bf16 exp(S) + row
// partials rsp[row][256] (p2=bx*32+wc*16+lr) + col partials csp[p][8192]
// (p=by*16+wr*4+lg); requires grid (8,4,8), bf16 out. Grid total % 8 == 0.
template<int BIAS, int OUTF32, int STATS>
__global__ __launch_bounds__(512, 2) void gemm256(
    const unsigned short* __restrict__ A0, const unsigned short* __restrict__ Bt0,
    long sA, long sB, int lda, int ldb,
    void* __restrict__ Cv0, long sC, int ldc,
    const float* __restrict__ bias, int nt1,
    float* __restrict__ csp, float* __restrict__ rsp)
{
    __shared__ __align__(16) unsigned short As[3][16384];   // 96 KB
    __shared__ __align__(16) unsigned short Bs[3][8192];    // 48 KB

    const int gx = gridDim.x, gy = gridDim.y;
    const int nwg = gx * gy * gridDim.z;
    int d = blockIdx.x + gx * (blockIdx.y + gy * blockIdx.z);
    int swz = (d & 7) * (nwg >> 3) + (d >> 3);
    const int bx = swz % gx; int tq = swz / gx;
    const int by = tq % gy;  const int bz = tq / gy;

    const int b  = bz;
    const int m0 = by * 256;
    const int n0 = bx * 128;
    const int t  = threadIdx.x;
    const int w  = t >> 6, l = t & 63;
    const int wr = w >> 1, wc = w & 1;          // 4 M-waves x 2 N-waves
    const int lr = l & 15, lg = l >> 4;

    const unsigned short* A0b = A0  + (long)b * sA;
    const unsigned short* B0b = Bt0 + (long)b * sB;

    const int rl  = l >> 3;
    const int gsw = ((l & 7) ^ (rl & 7)) * 8;

    const int NT = nt1;

    auto stageA = [&](int sp, int bf) {
        const int kt = sp * 64;
        #pragma unroll
        for (int i = 0; i < 4; ++i) {
            const int rb = w*32 + i*8;
            __builtin_amdgcn_global_load_lds(GAS(A0b + (long)(m0 + rb + rl)*lda + kt + gsw),
                                             LAS(&As[bf][rb*64]), 16, 0, 0);
        }
    };
    auto stageB = [&](int sp, int bf) {
        const int kt = sp * 64;
        #pragma unroll
        for (int i = 0; i < 2; ++i) {
            const int rb = w*16 + i*8;
            __builtin_amdgcn_global_load_lds(GAS(B0b + (long)(n0 + rb + rl)*ldb + kt + gsw),
                                             LAS(&Bs[bf][rb*64]), 16, 0, 0);
        }
    };

    f4 acc[4][4];
    #pragma unroll
    for (int i = 0; i < 4; ++i)
        #pragma unroll
        for (int j = 0; j < 4; ++j) acc[i][j] = (f4){0.f, 0.f, 0.f, 0.f};

    stageA(0, 0); stageB(0, 0);
    stageA(1, 1); stageB(1, 1);
    asm volatile("s_waitcnt vmcnt(6)" ::: "memory");
    __builtin_amdgcn_sched_barrier(0);
    __builtin_amdgcn_s_barrier();

    s8 a0[4], b0[4], a1f[4], b1f[4];

    #pragma unroll
    for (int m = 0; m < 4; ++m) {
        const int R = wr*64 + m*16 + lr;
        a0[m] = *(const s8*)&As[0][R*64 + ((lg ^ (R & 7)) * 8)];
    }
    #pragma unroll
    for (int n = 0; n < 4; ++n) {
        const int R = wc*64 + n*16 + lr;
        b0[n] = *(const s8*)&Bs[0][R*64 + ((lg ^ (R & 7)) * 8)];
    }
    asm volatile("s_waitcnt lgkmcnt(0)" ::: "memory");
    __builtin_amdgcn_sched_barrier(0);

    int buf = 0;
    for (int s = 0; s < NT; ++s) {
        int bn = buf + 2; if (bn >= 3) bn -= 3;
        int bx1 = buf + 1; if (bx1 >= 3) bx1 -= 3;

        #pragma unroll
        for (int m = 0; m < 4; ++m) {
            const int R = wr*64 + m*16 + lr;
            a1f[m] = *(const s8*)&As[buf][R*64 + (((4 + lg) ^ (R & 7)) * 8)];
        }
        #pragma unroll
        for (int n = 0; n < 4; ++n) {
            const int R = wc*64 + n*16 + lr;
            b1f[n] = *(const s8*)&Bs[buf][R*64 + (((4 + lg) ^ (R & 7)) * 8)];
        }
        if (s + 2 < NT) stageA(s + 2, bn);
        __builtin_amdgcn_s_setprio(1);
        #pragma unroll
        for (int m = 0; m < 4; ++m)
            #pragma unroll
            for (int n = 0; n < 4; ++n)
                acc[m][n] = __builtin_amdgcn_mfma_f32_16x16x32_bf16(a0[m], b0[n], acc[m][n], 0, 0, 0);
        __builtin_amdgcn_s_setprio(0);
        asm volatile("s_waitcnt lgkmcnt(0)" ::: "memory");
        __builtin_amdgcn_sched_barrier(0);

        if (s + 1 < NT) {
            if (s + 2 < NT) asm volatile("s_waitcnt vmcnt(4)" ::: "memory");
            else            asm volatile("s_waitcnt vmcnt(0)" ::: "memory");
            __builtin_amdgcn_sched_barrier(0);
            __builtin_amdgcn_s_barrier();
            #pragma unroll
            for (int m = 0; m < 4; ++m) {
                const int R = wr*64 + m*16 + lr;
                a0[m] = *(const s8*)&As[bx1][R*64 + ((lg ^ (R & 7)) * 8)];
            }
            #pragma unroll
            for (int n = 0; n < 4; ++n) {
                const int R = wc*64 + n*16 + lr;
                b0[n] = *(const s8*)&Bs[bx1][R*64 + ((lg ^ (R & 7)) * 8)];
            }
            if (s + 2 < NT) stageB(s + 2, bn);
            __builtin_amdgcn_s_setprio(1);
            #pragma unroll
            for (int m = 0; m < 4; ++m)
                #pragma unroll
                for (int n = 0; n < 4; ++n)
                    acc[m][n] = __builtin_amdgcn_mfma_f32_16x16x32_bf16(a1f[m], b1f[n], acc[m][n], 0, 0, 0);
            __builtin_amdgcn_s_setprio(0);
            asm volatile("s_waitcnt lgkmcnt(0)" ::: "memory");
            __builtin_amdgcn_sched_barrier(0);
        } else {
            __builtin_amdgcn_s_setprio(1);
            #pragma unroll
            for (int m = 0; m < 4; ++m)
                #pragma unroll
                for (int n = 0; n < 4; ++n)
                    acc[m][n] = __builtin_amdgcn_mfma_f32_16x16x32_bf16(a1f[m], b1f[n], acc[m][n], 0, 0, 0);
            __builtin_amdgcn_s_setprio(0);
        }

        buf = bx1;
    }

    const int rbase = lg * 4;
    float csum[4] = {0.f, 0.f, 0.f, 0.f};
    float rsum[16];
    #pragma unroll
    for (int i = 0; i < 16; ++i) rsum[i] = 0.f;

    #pragma unroll
    for (int m = 0; m < 4; ++m) {
        #pragma unroll
        for (int n = 0; n < 4; ++n) {
            const int row  = m0 + wr*64 + m*16 + rbase;
            const int col  = n0 + wc*64 + n*16 + lr;
            #pragma unroll
            for (int j = 0; j < 4; ++j) {
                float v = acc[m][n][j];
                if (BIAS == 1) v += bias[row + j];
                else if (BIAS == 2) v += bias[col];
                const long idx = (long)b*sC + (long)(row + j)*ldc + col;
                if (STATS) {
                    float ev = __expf(v);
                    unsigned short bv = f2bf(ev);
                    ((unsigned short*)Cv0)[idx] = bv;
                    float evr = bf2f(bv);
                    csum[n] += evr;
                    rsum[m*4 + j] += evr;
                } else if (OUTF32) {
                    ((float*)Cv0)[idx] = v;
                } else {
                    ((unsigned short*)Cv0)[idx] = f2bf(v);
                }
            }
        }
    }

    if (STATS) {
        const int p = by*16 + wr*4 + lg;          // 64 col-partials
        #pragma unroll
        for (int n = 0; n < 4; ++n) {
            const int col = n0 + wc*64 + n*16 + lr;
            csp[(long)p*8192 + b*1024 + col] = csum[n];
        }
        const int p2 = bx*32 + wc*16 + lr;        // 256 row-partials
        #pragma unroll
        for (int m = 0; m < 4; ++m)
            #pragma unroll
            for (int j = 0; j < 4; ++j) {
                const int row = m0 + wr*64 + m*16 + rbase + j;
                rsp[(long)(b*1024 + row)*256 + p2] = rsum[m*4 + j];
            }
    }
}

// ---------------- dual-accumulator GEMM: PT = s1(col)*A0B0 + s2(row)*A1B1 -----
__global__ __launch_bounds__(512, 2) void gemm_dual2(
    const unsigned short* __restrict__ A0, const unsigned short* __restrict__ Bt0,
    const unsigned short* __restrict__ A1, const unsigned short* __restrict__ Bt1,
    const float* __restrict__ rs, const float* __restrict__ cs,
    const float* __restrict__ alpha_p, const float* __restrict__ beta_p,
    unsigned short* __restrict__ C)
{
    constexpr int NT = 32;
    __shared__ __align__(16) unsigned short As[3][16384];
    __shared__ __align__(16) unsigned short Bs[3][8192];

    const int gx = gridDim.x, gy = gridDim.y;
    const int nwg = gx * gy * gridDim.z;
    int d = blockIdx.x + gx * (blockIdx.y + gy * blockIdx.z);
    int swz = (d & 7) * (nwg >> 3) + (d >> 3);
    const int bx = swz % gx; int tq = swz / gx;
    const int by = tq % gy;  const int bz = tq / gy;

    const int b  = bz;
    const int m0 = by * 256;
    const int n0 = bx * 128;
    const int t  = threadIdx.x;
    const int w  = t >> 6, l = t & 63;
    const int wr = w >> 1, wc = w & 1;
    const int lr = l & 15, lg = l >> 4;

    const unsigned short* A0b = A0  + (long)b * 1048576;
    const unsigned short* B0b = Bt0 + (long)b * 1048576;
    const unsigned short* A1b = A1  + (long)b * 1048576;
    const unsigned short* B1b = Bt1 + (long)b * 1048576;

    const int rl  = l >> 3;
    const int gsw = ((l & 7) ^ (rl & 7)) * 8;

    auto stageA = [&](int sp, int bf) {
        const unsigned short* Ap = (sp >= 16) ? A1b : A0b;
        const int kt = ((sp >= 16) ? sp - 16 : sp) * 64;
        #pragma unroll
        for (int i = 0; i < 4; ++i) {
            const int rb = w*32 + i*8;
            __builtin_amdgcn_global_load_lds(GAS(Ap + (long)(m0 + rb + rl)*1024 + kt + gsw),
                                             LAS(&As[bf][rb*64]), 16, 0, 0);
        }
    };
    auto stageB = [&](int sp, int bf) {
        const unsigned short* Bp = (sp >= 16) ? B1b : B0b;
        const int kt = ((sp >= 16) ? sp - 16 : sp) * 64;
        #pragma unroll
        for (int i = 0; i < 2; ++i) {
            const int rb = w*16 + i*8;
            __builtin_amdgcn_global_load_lds(GAS(Bp + (long)(n0 + rb + rl)*1024 + kt + gsw),
                                             LAS(&Bs[bf][rb*64]), 16, 0, 0);
        }
    };

    f4 acc1[4][4], acc2[4][4];
    #pragma unroll
    for (int i = 0; i < 4; ++i)
        #pragma unroll
        for (int j = 0; j < 4; ++j) {
            acc1[i][j] = (f4){0.f, 0.f, 0.f, 0.f};
            acc2[i][j] = (f4){0.f, 0.f, 0.f, 0.f};
        }

    stageA(0, 0); stageB(0, 0);
    stageA(1, 1); stageB(1, 1);
    asm volatile("s_waitcnt vmcnt(6)" ::: "memory");
    __builtin_amdgcn_sched_barrier(0);
    __builtin_amdgcn_s_barrier();

    s8 a0[4], b0[4], a1f[4], b1f[4];

    #pragma unroll
    for (int m = 0; m < 4; ++m) {
        const int R = wr*64 + m*16 + lr;
        a0[m] = *(const s8*)&As[0][R*64 + ((lg ^ (R & 7)) * 8)];
    }
    #pragma unroll
    for (int n = 0; n < 4; ++n) {
        const int R = wc*64 + n*16 + lr;
        b0[n] = *(const s8*)&Bs[0][R*64 + ((lg ^ (R & 7)) * 8)];
    }
    asm volatile("s_waitcnt lgkmcnt(0)" ::: "memory");
    __builtin_amdgcn_sched_barrier(0);

#define DUAL_BODY(ACC)                                                            \
    {                                                                             \
        int bn = buf + 2; if (bn >= 3) bn -= 3;                                   \
        int bx1 = buf + 1; if (bx1 >= 3) bx1 -= 3;                                \
        _Pragma("unroll")                                                         \
        for (int m = 0; m < 4; ++m) {                                             \
            const int R = wr*64 + m*16 + lr;                                      \
            a1f[m] = *(const s8*)&As[buf][R*64 + (((4 + lg) ^ (R & 7)) * 8)];     \
        }                                                                         \
        _Pragma("unroll")                                                         \
        for (int n = 0; n < 4; ++n) {                                             \
            const int R = wc*64 + n*16 + lr;                                      \
            b1f[n] = *(const s8*)&Bs[buf][R*64 + (((4 + lg) ^ (R & 7)) * 8)];     \
        }                                                                         \
        if (s + 2 < NT) stageA(s + 2, bn);                                        \
        __builtin_amdgcn_s_setprio(1);                                            \
        _Pragma("unroll")                                                         \
        for (int m = 0; m < 4; ++m)                                               \
            _Pragma("unroll")                                                     \
            for (int n = 0; n < 4; ++n)                                           \
                ACC[m][n] = __builtin_amdgcn_mfma_f32_16x16x32_bf16(a0[m], b0[n], ACC[m][n], 0, 0, 0); \
        __builtin_amdgcn_s_setprio(0);                                            \
        asm volatile("s_waitcnt lgkmcnt(0)" ::: "memory");                        \
        __builtin_amdgcn_sched_barrier(0);                                        \
        if (s + 1 < NT) {                                                         \
            if (s + 2 < NT) asm volatile("s_waitcnt vmcnt(4)" ::: "memory");      \
            else            asm volatile("s_waitcnt vmcnt(0)" ::: "memory");      \
            __builtin_amdgcn_sched_barrier(0);                                    \
            __builtin_amdgcn_s_barrier();                                         \
            _Pragma("unroll")                                                     \
            for (int m = 0; m < 4; ++m) {                                         \
                const int R = wr*64 + m*16 + lr;                                  \
                a0[m] = *(const s8*)&As[bx1][R*64 + ((lg ^ (R & 7)) * 8)];        \
            }                                                                     \
            _Pragma("unroll")                                                     \
            for (int n = 0; n < 4; ++n) {                                         \
                const int R = wc*64 + n*16 + lr;                                  \
                b0[n] = *(const s8*)&Bs[bx1][R*64 + ((lg ^ (R & 7)) * 8)];        \
            }                                                                     \
            if (s + 2 < NT) stageB(s + 2, bn);                                    \
            __builtin_amdgcn_s_setprio(1);                                        \
            _Pragma("unroll")                                                     \
            for (int m = 0; m < 4; ++m)                                           \
                _Pragma("unroll")                                                 \
                for (int n = 0; n < 4; ++n)                                       \
                    ACC[m][n] = __builtin_amdgcn_mfma_f32_16x16x32_bf16(a1f[m], b1f[n], ACC[m][n], 0, 0, 0); \
            __builtin_amdgcn_s_setprio(0);                                        \
            asm volatile("s_waitcnt lgkmcnt(0)" ::: "memory");                    \
            __builtin_amdgcn_sched_barrier(0);                                    \
        } else {                                                                  \
            __builtin_amdgcn_s_setprio(1);                                        \
            _Pragma("unroll")                                                     \
            for (int m = 0; m < 4; ++m)                                           \
                _Pragma("unroll")                                                 \
                for (int n = 0; n < 4; ++n)                                       \
                    ACC[m][n] = __builtin_amdgcn_mfma_f32_16x16x32_bf16(a1f[m], b1f[n], ACC[m][n], 0, 0, 0); \
            __builtin_amdgcn_s_setprio(0);                                        \
        }                                                                         \
        buf = bx1;                                                                \
    }

    int buf = 0;
    for (int s = 0; s < 16; ++s) DUAL_BODY(acc1)
    for (int s = 16; s < NT; ++s) DUAL_BODY(acc2)
#undef DUAL_BODY

    const float al = alpha_p[0], be = beta_p[0];
    const int rbase = lg * 4;
    float rscv[4];
    #pragma unroll
    for (int n = 0; n < 4; ++n)
        rscv[n] = al / rs[b*1024 + n0 + wc*64 + n*16 + lr];

    #pragma unroll
    for (int m = 0; m < 4; ++m) {
        #pragma unroll
        for (int j = 0; j < 4; ++j) {
            const int row = m0 + wr*64 + m*16 + rbase + j;
            const float csc = be / cs[b*1024 + row];
            #pragma unroll
            for (int n = 0; n < 4; ++n) {
                const int col = n0 + wc*64 + n*16 + lr;
                float v = acc1[m][n][j]*rscv[n] + acc2[m][n][j]*csc;
                C[(long)b*1048576 + (long)row*1024 + col] = f2bf(v);
            }
        }
    }
}

// ---------------- 128x128 pipelined GEMM (out projection) ---------------------
template<int BIAS, int OUTF32, int NT1, int NBUF>
__global__ __launch_bounds__(256) void gemm_pipe(
    const unsigned short* __restrict__ A0, const unsigned short* __restrict__ Bt0,
    long sA, long sB, int lda, int ldb,
    void* __restrict__ Cv0, long sC, int ldc,
    const float* __restrict__ bias)
{
    constexpr int NT = NT1;
    __shared__ __align__(16) unsigned short As[NBUF][4096];
    __shared__ __align__(16) unsigned short Bs[NBUF][4096];

    const int gx = gridDim.x, gy = gridDim.y;
    const int nwg = gx * gy * gridDim.z;
    int d = blockIdx.x + gx * (blockIdx.y + gy * blockIdx.z);
    int swz = (d & 7) * (nwg >> 3) + (d >> 3);
    const int bx = swz % gx; int tq = swz / gx;
    const int by = tq % gy;  const int bz = tq / gy;

    const int b  = bz;
    const int m0 = by * 128;
    const int n0 = bx * 128;
    const int t  = threadIdx.x;
    const int w  = t >> 6, l = t & 63;
    const int wr = w >> 1, wc = w & 1;
    const int lr = l & 15;

    const unsigned short* A0b = A0  + (long)b * sA;
    const unsigned short* B0b = Bt0 + (long)b * sB;

    const int rA   = w*32 + (l >> 2);
    const int cswz = ((l & 3) ^ ((l >> 3) & 3)) * 8;
    const int swzr = (((l >> 4) ^ ((lr >> 1) & 3)) * 8);

    f4 acc[4][4];
    #pragma unroll
    for (int i = 0; i < 4; ++i)
        #pragma unroll
        for (int j = 0; j < 4; ++j) acc[i][j] = (f4){0.f, 0.f, 0.f, 0.f};

    auto stage = [&](int sp, int bf) {
        const int kt = sp * 32;
        __builtin_amdgcn_global_load_lds(GAS(A0b + (long)(m0 + rA     )*lda + kt + cswz), LAS(&As[bf][w*1024      ]), 16, 0, 0);
        __builtin_amdgcn_global_load_lds(GAS(A0b + (long)(m0 + rA + 16)*lda + kt + cswz), LAS(&As[bf][w*1024 + 512]), 16, 0, 0);
        __builtin_amdgcn_global_load_lds(GAS(B0b + (long)(n0 + rA     )*ldb + kt + cswz), LAS(&Bs[bf][w*1024      ]), 16, 0, 0);
        __builtin_amdgcn_global_load_lds(GAS(B0b + (long)(n0 + rA + 16)*ldb + kt + cswz), LAS(&Bs[bf][w*1024 + 512]), 16, 0, 0);
    };

    #pragma unroll
    for (int dpl = 0; dpl < NBUF - 1; ++dpl) stage(dpl, dpl);

    int buf = 0;
    for (int s = 0; s < NT; ++s) {
        if (NBUF >= 4 && s + 2 < NT) asm volatile("s_waitcnt vmcnt(8)" ::: "memory");
        else if (s + 1 < NT)         asm volatile("s_waitcnt vmcnt(4)" ::: "memory");
        else                         asm volatile("s_waitcnt vmcnt(0)" ::: "memory");
        __builtin_amdgcn_s_barrier();
        __builtin_amdgcn_sched_barrier(0);

        s8 aF[4], bF[4];
        #pragma unroll
        for (int m = 0; m < 4; ++m) aF[m] = *(const s8*)&As[buf][(wr*64 + m*16 + lr)*32 + swzr];
        #pragma unroll
        for (int n = 0; n < 4; ++n) bF[n] = *(const s8*)&Bs[buf][(wc*64 + n*16 + lr)*32 + swzr];

        if (s + NBUF - 1 < NT) {
            int bn = buf + NBUF - 1; if (bn >= NBUF) bn -= NBUF;
            stage(s + NBUF - 1, bn);
        }

        __builtin_amdgcn_s_setprio(1);
        #pragma unroll
        for (int m = 0; m < 4; ++m)
            #pragma unroll
            for (int n = 0; n < 4; ++n)
                acc[m][n] = __builtin_amdgcn_mfma_f32_16x16x32_bf16(aF[m], bF[n], acc[m][n], 0, 0, 0);
        __builtin_amdgcn_s_setprio(0);

        if (++buf == NBUF) buf = 0;
    }

    const int rbase = (l >> 4) * 4;
    #pragma unroll
    for (int m = 0; m < 4; ++m) {
        #pragma unroll
        for (int n = 0; n < 4; ++n) {
            const int row = m0 + wr*64 + m*16 + rbase;
            const int col = n0 + wc*64 + n*16 + lr;
            #pragma unroll
            for (int j = 0; j < 4; ++j) {
                float v = acc[m][n][j];
                if (BIAS == 1) v += bias[row + j];
                else if (BIAS == 2) v += bias[col];
                const long idx = (long)b*sC + (long)(row + j)*ldc + col;
                if (OUTF32) ((float*)Cv0)[idx] = v;
                else ((unsigned short*)Cv0)[idx] = f2bf(v);
            }
        }
    }
}

// ---------------- stats reduce: cs[q] = sum csp; rs[row] = sum rsp ------------
__global__ __launch_bounds__(256) void stats_reduce(
    const float* __restrict__ csp, const float* __restrict__ rsp,
    float* __restrict__ cs, float* __restrict__ rs)
{
    if (blockIdx.x < 32) {
        const int q = blockIdx.x * 256 + threadIdx.x;   // 8192
        float s = 0.f;
        #pragma unroll
        for (int p = 0; p < 64; ++p) s += csp[(long)p*8192 + q];
        cs[q] = s;
    } else {
        const int blk = blockIdx.x - 32;                // 0..511, 16 rows each
        const int w = threadIdx.x >> 6, l = threadIdx.x & 63;
        #pragma unroll
        for (int i = 0; i < 4; ++i) {
            const int row = blk*16 + w*4 + i;
            f4 v = *(const f4*)&rsp[(long)row*256 + l*4];
            float s = v[0] + v[1] + v[2] + v[3];
            #pragma unroll
            for (int off = 32; off; off >>= 1) s += __shfl_xor(s, off);
            if (l == 0) rs[row] = s;
        }
    }
}

// ---------------- Et = E^T per batch (bf16 LDS transpose) ---------------------
__global__ __launch_bounds__(256) void et_trans(
    const unsigned short* __restrict__ E, unsigned short* __restrict__ Et)
{
    __shared__ unsigned short tile[64][65];
    const int b  = blockIdx.z;
    const int i0 = blockIdx.x * 64;
    const int q0 = blockIdx.y * 64;
    const int t  = threadIdx.x;
    const int ch = t & 7, r = t >> 3;    // r 0..31
    const unsigned short* Eb = E + (long)b * 1048576;
    #pragma unroll
    for (int pp = 0; pp < 2; ++pp) {
        const int rr = r + pp*32;
        us8 v = *(const us8*)&Eb[(long)(i0 + rr)*1024 + q0 + ch*8];
        #pragma unroll
        for (int e = 0; e < 8; ++e) tile[rr][ch*8 + e] = v[e];
    }
    __syncthreads();
    unsigned short* Etb = Et + (long)b * 1048576;
    #pragma unroll
    for (int pp = 0; pp < 2; ++pp) {
        const int qr = r + pp*32;
        us8 o;
        #pragma unroll
        for (int e = 0; e < 8; ++e) o[e] = tile[ch*8 + e][qr];
        *(us8*)&Etb[(long)(q0 + qr)*1024 + i0 + ch*8] = o;
    }
}

// -----------------------------------------------------------------------------
extern "C" void kernel_launch(void* const* d_in, const int* in_sizes, int n_in,
                              void* d_out, int out_size, void* d_ws, size_t ws_size,
                              hipStream_t stream)
{
    const float* x     = (const float*)d_in[0];
    const float* w1    = (const float*)d_in[1];
    const float* b1    = (const float*)d_in[2];
    const float* wq    = (const float*)d_in[3];
    const float* bq    = (const float*)d_in[4];
    const float* wv    = (const float*)d_in[5];
    const float* bv    = (const float*)d_in[6];
    const float* w2    = (const float*)d_in[7];
    const float* b2    = (const float*)d_in[8];
    const float* alpha = (const float*)d_in[9];
    const float* beta  = (const float*)d_in[10];
    float* out = (float*)d_out;

    char* ws = (char*)d_ws;
    size_t off = 0;
    auto alloc = [&](size_t bytes) -> void* {
        void* p = ws + off; off += (bytes + 255) & ~(size_t)255; return p;
    };
    unsigned short* w1b   = (unsigned short*)alloc(1024L*256*2);      // .5 MB
    unsigned short* wqvb  = (unsigned short*)alloc(2048L*1024*2);     //  4 MB (wq||wv)
    unsigned short* w2b   = (unsigned short*)alloc(256L*1024*2);      // .5 MB
    float*          biasqv= (float*)alloc(2048L*4);                   //  8 KB
    float*          cspv  = (float*)alloc(64L*8192*4);                //  2 MB
    float*          rspv  = (float*)alloc(8192L*256*4);               //  8 MB
    float*          csv   = (float*)alloc(8L*1024*4);                 // 32 KB
    float*          rsv   = (float*)alloc(8L*1024*4);                 // 32 KB
    unsigned short* xTb   = (unsigned short*)alloc(8L*1024*256*2);    //  4 MB
    unsigned short* x1b   = (unsigned short*)alloc(8L*1024*1024*2);   // 16 MB
    unsigned short* x1tb  = (unsigned short*)alloc(8L*1024*1024*2);   // 16 MB
    unsigned short* gtb   = (unsigned short*)alloc(8L*1024*1024*2);   // 16 MB
    unsigned short* rtb   = (unsigned short*)alloc(8L*1024*1024*2);   // 16 MB
    unsigned short* Ptb   = (unsigned short*)alloc(8L*1024*1024*2);   // 16 MB
    // lifetime aliases:
    unsigned short* Eb  = x1tb;   // x1tb (x1T) dead after gT|rT GEMM -> E
    unsigned short* Etb = gtb;    // gtb (gT) dead after E GEMM -> Et

    const long S1M = 1048576;

    // prep: weights + bias concat + x transpose (one dispatch)
    prep<<<4610, 256, 0, stream>>>(w1, wq, wv, w2, w1b, wqvb, wqvb + S1M, w2b,
                                   bq, bv, biasqv, x, xTb);

    // x1 = w1·xT^T + b1(row)               [chan,hw], z-batched (256 blocks)
    gemm256<1,0,0><<<dim3(8, 4, 8), 512, 0, stream>>>(
        w1b, xTb, 0, 262144, 256, 256, x1b, S1M, 1024, b1, 4, nullptr, nullptr);
    // x1T = xT·w1^T + b1(col)              stacked M=8192 (256 blocks)
    gemm256<2,0,0><<<dim3(8, 32, 1), 512, 0, stream>>>(
        xTb, w1b, 0, 0, 256, 256, x1tb, 0, 1024, b1, 4, nullptr, nullptr);
    // gT|rT = x1T·(wq||wv)^T + bias(col)   stacked M=8192, N=2048, split
    gemm8p<2,1><<<dim3(8, 32), 512, 0, stream>>>(
        x1tb, wqvb, 1024, 1024, gtb, rtb, 1024, biasqv);
    // E = bf16 exp(x1·gT^T) + row/col partials   z-batched (256 blocks)
    gemm256<0,0,1><<<dim3(8, 4, 8), 512, 0, stream>>>(
        x1b, gtb, S1M, S1M, 1024, 1024, Eb, S1M, 1024, nullptr, 16, cspv, rspv);
    // rs, cs
    stats_reduce<<<544, 256, 0, stream>>>(cspv, rspv, csv, rsv);
    // Et = E^T
    et_trans<<<dim3(16, 16, 8), 256, 0, stream>>>(Eb, Etb);
    // PT = (a/rs[col])·(rT·E^T) + (b/cs[row])·(Et·x1^T)   (256 blocks)
    gemm_dual2<<<dim3(8, 4, 8), 512, 0, stream>>>(
        rtb, Eb, Etb, x1b, rsv, csv, alpha, beta, Ptb);
    // out = w2·PT^T + b2(row), fp32        (128 blocks, depth-3)
    gemm_pipe<1,1,32,4><<<dim3(8, 2, 8), 256, 0, stream>>>(
        w2b, Ptb, 0, S1M, 1024, 1024, out, 262144, 1024, b2);
}